// Round 22
// baseline (72.618 us; speedup 1.0000x reference)
//
#include <hip/hip_runtime.h>
#include <hip/hip_bf16.h>

// Problem constants (fixed by setup_inputs)
constexpr int B_ = 8, C_ = 64, O_ = 64, H_ = 128, W_ = 128;
constexpr int K2_ = 9, OFFC = 18;          // 2*K2
constexpr int NPIX = B_ * H_ * W_;         // 131072

typedef __attribute__((ext_vector_type(8))) short bf16x8;
typedef __attribute__((ext_vector_type(4))) short bf16x4;
typedef __attribute__((ext_vector_type(4))) float f32x4;
typedef __attribute__((ext_vector_type(2))) float f32x2;

__device__ __forceinline__ unsigned short f2bf(float f) {
    unsigned int u = __float_as_uint(f);
    u += 0x7fffu + ((u >> 16) & 1u);       // round-to-nearest-even
    return (unsigned short)(u >> 16);
}
__device__ __forceinline__ float bf2f(unsigned short s) {
    return __uint_as_float(((unsigned)s) << 16);
}
__device__ __forceinline__ float tobf_f(float v) {   // round-trip through bf16
    return bf2f(f2bf(v));
}
__device__ __forceinline__ short f2bf_s(float f) {   // single-instr cvt path
    __hip_bfloat16 t = __float2bfloat16(f);
    return *reinterpret_cast<short*>(&t);
}
// Two packed bf16 (one u32) -> two f32: lo = u<<16, hi = u & 0xffff0000.
__device__ __forceinline__ f32x2 bfpair(unsigned u) {
    f32x2 r;
    r[0] = __uint_as_float(u << 16);
    r[1] = __uint_as_float(u & 0xffff0000u);
    return r;
}

// ---------------------------------------------------------------------------
// K0b: w_def (O,C,3,3) -> wTfrag, bf16 in MFMA B-fragment order.
// frag f = kc*4 + nt; lane l, elem j: oc = nt*16+(l&15); K = kc*32+(l>>4)*8+j
// K = tap*64 + c
// ---------------------------------------------------------------------------
__global__ void k_wprep(const float* __restrict__ w_def,
                        unsigned short* __restrict__ wTfrag) {
    int i = blockIdx.x * 256 + threadIdx.x;           // over 72*512 = 36864
    if (i >= O_ * C_ * K2_) return;
    int f = i >> 9;            // /512
    int l = (i >> 3) & 63;
    int j = i & 7;
    int kc = f >> 2, nt = f & 3;
    int oc = nt * 16 + (l & 15);
    int K  = kc * 32 + ((l >> 4) << 3) + j;
    int tap = K >> 6, c = K & 63;
    wTfrag[i] = f2bf(w_def[(size_t)oc * (C_ * K2_) + c * K2_ + tap]);
}

// ---------------------------------------------------------------------------
// K0c: w_off (18,C,3,3) -> wOfrag, bf16 B-fragment order, N padded 18->32.
// ---------------------------------------------------------------------------
__global__ void k_wprep_off(const float* __restrict__ w_off,
                            unsigned short* __restrict__ wOfrag) {
    int i = blockIdx.x * 256 + threadIdx.x;           // over 36*512 = 18432
    if (i >= 36 * 512) return;
    int f = i >> 9;
    int l = (i >> 3) & 63;
    int j = i & 7;
    int kc = f >> 1, nt = f & 1;
    int oc = nt * 16 + (l & 15);
    int K  = kc * 32 + ((l >> 4) << 3) + j;
    int tap = K >> 6, c = K & 63;
    float v = (oc < OFFC) ? w_off[((size_t)oc * C_ + c) * K2_ + tap] : 0.f;
    wOfrag[i] = f2bf(v);
}

// ---------------------------------------------------------------------------
// K1: fused. Block = 128 px (rows h,h+1 x 64 cols), 512 threads (8 waves).
// xs: x window rows h-2..h+3 (6), cols w0-3..w0+68 (72), bf16,
//     [q=ch/16][entry=(r,col)][16ch]; byte ^= ((col&7)<<4) ^ (q<<5).
//     Bijective: QS = 432*32, 432%8==0, 72%8==0 (round-5 proof carries).
// Wave w owns px subtile [w*16,+16) x ALL 64 oc.
// Round-22 (separates r19/r20's confounded variables): keep the pairwise
// sequential LOAD(t)/INTERP(t) cadence (corner registers die per-tap, so
// the r20 triples' 24-live-uint4 pressure peak never forms) but group FOUR
// taps per __any guard (regions 5 -> 3). Patches run after the 4th interp;
// they read only tap-local state and write alo/ahi consumed by the MFMAs
// in the same ascending-k order -> numerics bit-identical to r19.
// ---------------------------------------------------------------------------
constexpr int QS = 6 * 72 * 32;            // 13824 B per q partition (432 entries)
constexpr int XS_BYTES = 4 * QS;           // 55296

__global__ __launch_bounds__(512, 2) void k_fused(const float* __restrict__ x,
                                                  const unsigned short* __restrict__ wOfrag,
                                                  const float* __restrict__ b_off,
                                                  const unsigned short* __restrict__ wTfrag,
                                                  const float* __restrict__ b_def,
                                                  float* __restrict__ out) {
    __shared__ __align__(16) char xs[XS_BYTES];
    __shared__ float offsBuf[128][22];

    int bid = blockIdx.x;                  // grid = 1024; one image per XCD
    int swz = (bid & 7) * 128 + (bid >> 3);
    int b  = swz >> 7;                     // image
    int rem2 = swz & 127;
    int h  = (rem2 >> 1) << 1;             // even row; block covers h, h+1
    int w0 = (rem2 & 1) << 6;              // 0 or 64

    int tid  = threadIdx.x;
    int lane = tid & 63;
    int wave = tid >> 6;                   // 0..7

    // --- phase 0: stage x window -> xs (bf16, zero-padded OOB) ---
    {
        int col = tid % 72;
        int rem = tid / 72;
        for (int it = tid; it < 6912; it += 512) {
            int c4  = rem & 15;            // channel group of 4
            int r   = rem >> 4;            // 0..5
            int y    = h - 2 + r;
            int xcol = w0 - 3 + col;
            bf16x4 pk;
            if (((unsigned)y < (unsigned)H_) && ((unsigned)xcol < (unsigned)W_)) {
                const float* g = x + (((size_t)(b * C_ + c4 * 4) * H_ + y) * W_ + xcol);
                pk[0] = f2bf_s(g[0]);
                pk[1] = f2bf_s(g[H_ * W_]);
                pk[2] = f2bf_s(g[2 * H_ * W_]);
                pk[3] = f2bf_s(g[3 * H_ * W_]);
            } else {
                pk = (bf16x4){0, 0, 0, 0};
            }
            int q0 = c4 >> 2;
            int byte = q0 * QS + ((r * 72 + col) * 32) + (c4 & 3) * 8;
            byte ^= ((col & 7) << 4) ^ (q0 << 5);
            *reinterpret_cast<bf16x4*>(xs + byte) = pk;
            col += 8; rem += 7;
            if (col >= 72) { col -= 72; rem += 1; }
        }
    }
    __syncthreads();

    // --- phase 1: offset GEMM (A-frags straight from xs) -> offsBuf ---
    {
        f32x4 acc2[2];
        acc2[0] = (f32x4){0.f, 0.f, 0.f, 0.f};
        acc2[1] = (f32x4){0.f, 0.f, 0.f, 0.f};
        int g   = lane >> 4;
        int pxr = wave * 16 + (lane & 15);            // 0..127
        int rr  = pxr >> 6, cx = pxr & 63;
        #pragma unroll
        for (int kc = 0; kc < 18; ++kc) {
            int K   = kc * 32 + g * 8;
            int tap = K >> 6, c = K & 63;
            int ky = tap / 3, kx = tap % 3;
            int col = cx + kx + 2;
            int r   = rr + ky + 1;
            int qq  = c >> 4;
            int byte = qq * QS + ((r * 72 + col) * 32) + (c & 15) * 2;
            byte ^= ((col & 7) << 4) ^ (qq << 5);
            bf16x8 a  = *reinterpret_cast<const bf16x8*>(xs + byte);
            bf16x8 b0 = *reinterpret_cast<const bf16x8*>(wOfrag + (((kc * 2 + 0) * 64 + lane) << 3));
            bf16x8 b1 = *reinterpret_cast<const bf16x8*>(wOfrag + (((kc * 2 + 1) * 64 + lane) << 3));
            acc2[0] = __builtin_amdgcn_mfma_f32_16x16x32_bf16(a, b0, acc2[0], 0, 0, 0);
            acc2[1] = __builtin_amdgcn_mfma_f32_16x16x32_bf16(a, b1, acc2[1], 0, 0, 0);
        }
        #pragma unroll
        for (int nt = 0; nt < 2; ++nt) {
            int oc = nt * 16 + (lane & 15);
            if (oc < OFFC) {
                float bo = b_off[oc];
                #pragma unroll
                for (int j = 0; j < 4; ++j) {
                    int px = wave * 16 + ((lane >> 4) << 2) + j;
                    offsBuf[px][oc] = acc2[nt][j] + bo;
                }
            }
        }
    }
    __syncthreads();

    // --- phase 2: quad-guarded sample + MFMA (pairwise load cadence) ---
    f32x4 acc[4];
    #pragma unroll
    for (int nt = 0; nt < 4; ++nt) acc[nt] = (f32x4){0.f, 0.f, 0.f, 0.f};

    int g    = lane >> 4;                  // K-group 0..3
    int rowM = lane & 15;
    int pxw  = (wave << 4) + rowM;         // block-local px this lane samples
    int prr  = pxw >> 6, pcx = pxw & 63;   // sub-row (0/1), col in segment
    int glo  = (g & 1) << 4;               // byte offset of 8-ch half in entry
    int qlo  = g >> 1;                     // channels g*8..+8 -> q 0..1
    int qhi  = qlo + 2;                    // channels 32+g*8..+8 -> q 2..3
    int baseLo = qlo * QS + glo, baseHi = qhi * QS + glo;
    int xorLo  = qlo << 5,  xorHi  = qhi << 5;

    // preload all 9 offset pairs (one ds_read batch)
    float2 off9[9];
    #pragma unroll
    for (int k = 0; k < 9; ++k)
        off9[k] = *reinterpret_cast<const float2*>(&offsBuf[pxw][2 * k]);

// --- per-tap building blocks; S = name suffix, kk = tap index (literal) ---
#define TAPADDR(kk, S)                                                             \
    float py##S  = (float)(h + prr - 1 + ((kk) / 3)) + off9[kk].x;                 \
    float pxf##S = (float)(w0 + pcx - 1 + ((kk) % 3)) + off9[kk].y;                \
    float y0f##S = floorf(py##S), x0f##S = floorf(pxf##S);                         \
    float wy##S = py##S - y0f##S, wx##S = pxf##S - x0f##S;                         \
    int y0##S = (int)y0f##S, x0##S = (int)x0f##S;                                  \
    int r0##S = y0##S - (h - 2), c0##S = x0##S - (w0 - 3);                         \
    bool oow##S = ((unsigned)r0##S >= 5u) | ((unsigned)c0##S >= 71u);              \
    int rc##S = min(max(r0##S, 0), 4), cc##S = min(max(c0##S, 0), 70);             \
    float w00##S = (1.f - wy##S) * (1.f - wx##S);                                  \
    float w01##S = (1.f - wy##S) * wx##S;                                          \
    float w10##S = wy##S * (1.f - wx##S);                                          \
    float w11##S = wy##S * wx##S;                                                  \
    int A00##S = (rc##S * 72 + cc##S) << 5;                                        \
    int s0##S = (cc##S & 7) << 4;                                                  \
    int s1##S = ((cc##S + 1) & 7) << 4;

#define TAPLOAD(S)                                                                                 \
    uint4 l0##S = *reinterpret_cast<const uint4*>(xs + ((baseLo + A00##S)        ^ (s0##S ^ xorLo))); \
    uint4 l1##S = *reinterpret_cast<const uint4*>(xs + ((baseLo + A00##S + 32)   ^ (s1##S ^ xorLo))); \
    uint4 l2##S = *reinterpret_cast<const uint4*>(xs + ((baseLo + A00##S + 2304) ^ (s0##S ^ xorLo))); \
    uint4 l3##S = *reinterpret_cast<const uint4*>(xs + ((baseLo + A00##S + 2336) ^ (s1##S ^ xorLo))); \
    uint4 h0##S = *reinterpret_cast<const uint4*>(xs + ((baseHi + A00##S)        ^ (s0##S ^ xorHi))); \
    uint4 h1##S = *reinterpret_cast<const uint4*>(xs + ((baseHi + A00##S + 32)   ^ (s1##S ^ xorHi))); \
    uint4 h2##S = *reinterpret_cast<const uint4*>(xs + ((baseHi + A00##S + 2304) ^ (s0##S ^ xorHi))); \
    uint4 h3##S = *reinterpret_cast<const uint4*>(xs + ((baseHi + A00##S + 2336) ^ (s1##S ^ xorHi)));

#define TAPINTERP(S)                                                               \
    bf16x8 alo##S;                                                                 \
    {                                                                              \
        f32x2 L0 = bfpair(l0##S.x) * w00##S + bfpair(l1##S.x) * w01##S             \
                 + bfpair(l2##S.x) * w10##S + bfpair(l3##S.x) * w11##S;            \
        f32x2 L1 = bfpair(l0##S.y) * w00##S + bfpair(l1##S.y) * w01##S             \
                 + bfpair(l2##S.y) * w10##S + bfpair(l3##S.y) * w11##S;            \
        f32x2 L2 = bfpair(l0##S.z) * w00##S + bfpair(l1##S.z) * w01##S             \
                 + bfpair(l2##S.z) * w10##S + bfpair(l3##S.z) * w11##S;            \
        f32x2 L3 = bfpair(l0##S.w) * w00##S + bfpair(l1##S.w) * w01##S             \
                 + bfpair(l2##S.w) * w10##S + bfpair(l3##S.w) * w11##S;            \
        alo##S[0] = f2bf_s(L0[0]); alo##S[1] = f2bf_s(L0[1]);                      \
        alo##S[2] = f2bf_s(L1[0]); alo##S[3] = f2bf_s(L1[1]);                      \
        alo##S[4] = f2bf_s(L2[0]); alo##S[5] = f2bf_s(L2[1]);                      \
        alo##S[6] = f2bf_s(L3[0]); alo##S[7] = f2bf_s(L3[1]);                      \
    }                                                                              \
    bf16x8 ahi##S;                                                                 \
    {                                                                              \
        f32x2 H0 = bfpair(h0##S.x) * w00##S + bfpair(h1##S.x) * w01##S             \
                 + bfpair(h2##S.x) * w10##S + bfpair(h3##S.x) * w11##S;            \
        f32x2 H1 = bfpair(h0##S.y) * w00##S + bfpair(h1##S.y) * w01##S             \
                 + bfpair(h2##S.y) * w10##S + bfpair(h3##S.y) * w11##S;            \
        f32x2 H2 = bfpair(h0##S.z) * w00##S + bfpair(h1##S.z) * w01##S             \
                 + bfpair(h2##S.z) * w10##S + bfpair(h3##S.z) * w11##S;            \
        f32x2 H3 = bfpair(h0##S.w) * w00##S + bfpair(h1##S.w) * w01##S             \
                 + bfpair(h2##S.w) * w10##S + bfpair(h3##S.w) * w11##S;            \
        ahi##S[0] = f2bf_s(H0[0]); ahi##S[1] = f2bf_s(H0[1]);                      \
        ahi##S[2] = f2bf_s(H1[0]); ahi##S[3] = f2bf_s(H1[1]);                      \
        ahi##S[4] = f2bf_s(H2[0]); ahi##S[5] = f2bf_s(H2[1]);                      \
        ahi##S[6] = f2bf_s(H3[0]); ahi##S[7] = f2bf_s(H3[1]);                      \
    }

#define PATCHBODY(S)                                                               \
    {                                                                              \
        int y1 = y0##S + 1, x1 = x0##S + 1;                                        \
        bool vy0 = (y0##S >= 0) & (y0##S < H_);                                    \
        bool vy1 = (y1 >= 0) & (y1 < H_);                                          \
        bool vx0 = (x0##S >= 0) & (x0##S < W_);                                    \
        bool vx1 = (x1 >= 0) & (x1 < W_);                                          \
        float m00 = (vy0 && vx0) ? w00##S : 0.f;                                   \
        float m01 = (vy0 && vx1) ? w01##S : 0.f;                                   \
        float m10 = (vy1 && vx0) ? w10##S : 0.f;                                   \
        float m11 = (vy1 && vx1) ? w11##S : 0.f;                                   \
        int y0c = min(max(y0##S, 0), H_ - 1), y1c = min(max(y1, 0), H_ - 1);       \
        int x0c = min(max(x0##S, 0), W_ - 1), x1c = min(max(x1, 0), W_ - 1);       \
        int i00 = y0c * W_ + x0c, i01 = y0c * W_ + x1c;                            \
        int i10 = y1c * W_ + x0c, i11 = y1c * W_ + x1c;                            \
        const float* cb = x + (size_t)b * C_ * H_ * W_;                            \
        _Pragma("unroll")                                                          \
        for (int j = 0; j < 8; ++j) {                                              \
            const float* cA = cb + (size_t)((g << 3) + j) * (H_ * W_);             \
            const float* cB = cb + (size_t)(32 + (g << 3) + j) * (H_ * W_);        \
            alo##S[j] = f2bf_s(m00 * tobf_f(cA[i00]) + m01 * tobf_f(cA[i01])       \
                             + m10 * tobf_f(cA[i10]) + m11 * tobf_f(cA[i11]));     \
            ahi##S[j] = f2bf_s(m00 * tobf_f(cB[i00]) + m01 * tobf_f(cB[i01])       \
                             + m10 * tobf_f(cB[i10]) + m11 * tobf_f(cB[i11]));     \
        }                                                                          \
    }

#define TAPMFMA(kk, S)                                                             \
    {                                                                              \
        bf16x8 B0[4], B1[4];                                                       \
        _Pragma("unroll")                                                          \
        for (int nt = 0; nt < 4; ++nt) {                                           \
            B0[nt] = *reinterpret_cast<const bf16x8*>(                             \
                wTfrag + ((((2 * (kk) + 0) * 4 + nt) * 64 + lane) << 3));          \
            B1[nt] = *reinterpret_cast<const bf16x8*>(                             \
                wTfrag + ((((2 * (kk) + 1) * 4 + nt) * 64 + lane) << 3));          \
        }                                                                          \
        _Pragma("unroll")                                                          \
        for (int nt = 0; nt < 4; ++nt)                                             \
            acc[nt] = __builtin_amdgcn_mfma_f32_16x16x32_bf16(alo##S, B0[nt], acc[nt], 0, 0, 0); \
        _Pragma("unroll")                                                          \
        for (int nt = 0; nt < 4; ++nt)                                             \
            acc[nt] = __builtin_amdgcn_mfma_f32_16x16x32_bf16(ahi##S, B1[nt], acc[nt], 0, 0, 0); \
    }

#define QUAD(kA, kB, kC, kD)                                                       \
    {                                                                              \
        TAPADDR(kA, Qa) TAPADDR(kB, Qb) TAPADDR(kC, Qc) TAPADDR(kD, Qd)            \
        TAPLOAD(Qa) TAPINTERP(Qa)                                                  \
        TAPLOAD(Qb) TAPINTERP(Qb)                                                  \
        TAPLOAD(Qc) TAPINTERP(Qc)                                                  \
        TAPLOAD(Qd) TAPINTERP(Qd)                                                  \
        if (__any(oowQa | oowQb | oowQc | oowQd)) {                                \
            if (oowQa) PATCHBODY(Qa)                                               \
            if (oowQb) PATCHBODY(Qb)                                               \
            if (oowQc) PATCHBODY(Qc)                                               \
            if (oowQd) PATCHBODY(Qd)                                               \
        }                                                                          \
        TAPMFMA(kA, Qa) TAPMFMA(kB, Qb) TAPMFMA(kC, Qc) TAPMFMA(kD, Qd)            \
    }

#define SINGLE(kA)                                                                 \
    {                                                                              \
        TAPADDR(kA, Ps)                                                            \
        TAPLOAD(Ps)                                                                \
        TAPINTERP(Ps)                                                              \
        if (__any(oowPs)) {                                                        \
            if (oowPs) PATCHBODY(Ps)                                               \
        }                                                                          \
        TAPMFMA(kA, Ps)                                                            \
    }

    QUAD(0, 1, 2, 3)
    QUAD(4, 5, 6, 7)
    SINGLE(8)

#undef TAPADDR
#undef TAPLOAD
#undef TAPINTERP
#undef PATCHBODY
#undef TAPMFMA
#undef QUAD
#undef SINGLE

    // --- epilogue: direct float4 stores (proven r12/r13; r9's row split) ---
    int pxbase = (wave << 4) + (g << 2);   // 0..124, no 64-boundary crossing
    int rr = pxbase >> 6, cx = pxbase & 63;
    #pragma unroll
    for (int nt = 0; nt < 4; ++nt) {
        int oc = (nt << 4) + rowM;
        float bz = b_def[oc];
        float4 v;
        v.x = acc[nt][0] + bz;
        v.y = acc[nt][1] + bz;
        v.z = acc[nt][2] + bz;
        v.w = acc[nt][3] + bz;
        float* dst = out + (((size_t)b * O_ + oc) * H_ + h + rr) * W_ + w0 + cx;
        *reinterpret_cast<float4*>(dst) = v;
    }
}

// ---------------------------------------------------------------------------
extern "C" void kernel_launch(void* const* d_in, const int* in_sizes, int n_in,
                              void* d_out, int out_size, void* d_ws, size_t ws_size,
                              hipStream_t stream) {
    const float* x     = (const float*)d_in[0];
    const float* w_off = (const float*)d_in[1];
    const float* b_off = (const float*)d_in[2];
    const float* w_def = (const float*)d_in[3];
    const float* b_def = (const float*)d_in[4];
    float* out = (float*)d_out;

    char* ws = (char*)d_ws;
    unsigned short* wTf = (unsigned short*)ws;            // 73,728 B
    unsigned short* wOf = (unsigned short*)(ws + 73728);  // 36,864 B

    k_wprep<<<(O_ * C_ * K2_ + 255) / 256, 256, 0, stream>>>(w_def, wTf);
    k_wprep_off<<<(36 * 512 + 255) / 256, 256, 0, stream>>>(w_off, wOf);
    k_fused<<<NPIX / 128, 512, 0, stream>>>(x, wOf, b_off, wTf, b_def, out);
}

// Round 23
// 61.841 us; speedup vs baseline: 1.1743x; 1.1743x over previous
//
#include <hip/hip_runtime.h>
#include <hip/hip_bf16.h>

// Problem constants (fixed by setup_inputs)
constexpr int B_ = 8, C_ = 64, O_ = 64, H_ = 128, W_ = 128;
constexpr int K2_ = 9, OFFC = 18;          // 2*K2
constexpr int NPIX = B_ * H_ * W_;         // 131072

typedef __attribute__((ext_vector_type(8))) short bf16x8;
typedef __attribute__((ext_vector_type(4))) short bf16x4;
typedef __attribute__((ext_vector_type(4))) float f32x4;
typedef __attribute__((ext_vector_type(2))) float f32x2;

__device__ __forceinline__ unsigned short f2bf(float f) {
    unsigned int u = __float_as_uint(f);
    u += 0x7fffu + ((u >> 16) & 1u);       // round-to-nearest-even
    return (unsigned short)(u >> 16);
}
__device__ __forceinline__ float bf2f(unsigned short s) {
    return __uint_as_float(((unsigned)s) << 16);
}
__device__ __forceinline__ float tobf_f(float v) {   // round-trip through bf16
    return bf2f(f2bf(v));
}
__device__ __forceinline__ short f2bf_s(float f) {   // single-instr cvt path
    __hip_bfloat16 t = __float2bfloat16(f);
    return *reinterpret_cast<short*>(&t);
}
// Two packed bf16 (one u32) -> two f32: lo = u<<16, hi = u & 0xffff0000.
__device__ __forceinline__ f32x2 bfpair(unsigned u) {
    f32x2 r;
    r[0] = __uint_as_float(u << 16);
    r[1] = __uint_as_float(u & 0xffff0000u);
    return r;
}

// ---------------------------------------------------------------------------
// K0b: w_def (O,C,3,3) -> wTfrag, bf16 in MFMA B-fragment order.
// frag f = kc*4 + nt; lane l, elem j: oc = nt*16+(l&15); K = kc*32+(l>>4)*8+j
// K = tap*64 + c
// ---------------------------------------------------------------------------
__global__ void k_wprep(const float* __restrict__ w_def,
                        unsigned short* __restrict__ wTfrag) {
    int i = blockIdx.x * 256 + threadIdx.x;           // over 72*512 = 36864
    if (i >= O_ * C_ * K2_) return;
    int f = i >> 9;            // /512
    int l = (i >> 3) & 63;
    int j = i & 7;
    int kc = f >> 2, nt = f & 3;
    int oc = nt * 16 + (l & 15);
    int K  = kc * 32 + ((l >> 4) << 3) + j;
    int tap = K >> 6, c = K & 63;
    wTfrag[i] = f2bf(w_def[(size_t)oc * (C_ * K2_) + c * K2_ + tap]);
}

// ---------------------------------------------------------------------------
// K0c: w_off (18,C,3,3) -> wOfrag, bf16 B-fragment order, N padded 18->32.
// ---------------------------------------------------------------------------
__global__ void k_wprep_off(const float* __restrict__ w_off,
                            unsigned short* __restrict__ wOfrag) {
    int i = blockIdx.x * 256 + threadIdx.x;           // over 36*512 = 18432
    if (i >= 36 * 512) return;
    int f = i >> 9;
    int l = (i >> 3) & 63;
    int j = i & 7;
    int kc = f >> 1, nt = f & 1;
    int oc = nt * 16 + (l & 15);
    int K  = kc * 32 + ((l >> 4) << 3) + j;
    int tap = K >> 6, c = K & 63;
    float v = (oc < OFFC) ? w_off[((size_t)oc * C_ + c) * K2_ + tap] : 0.f;
    wOfrag[i] = f2bf(v);
}

// ---------------------------------------------------------------------------
// K1: fused. Block = 128 px (rows h,h+1 x 64 cols), 512 threads (8 waves).
// xs: x window rows h-2..h+3 (6), cols w0-3..w0+68 (72), bf16,
//     [q=ch/16][entry=(r,col)][16ch]; byte ^= ((col&7)<<4) ^ (q<<5).
//     Bijective: QS = 432*32, 432%8==0, 72%8==0 (round-5 proof carries).
// Wave w owns px subtile [w*16,+16) x ALL 64 oc.
// FINAL (= round-19, twice reproduced at 62.2/62.1 us):
// taps merged PAIRWISE into one scheduling region (region count 9->5).
// The region-merge curve is fully mapped: singles 68.5 / pairs 62.2 /
// triples 73.6 / quads 72.6 — pairs is the optimum (beyond it, live-range
// extension across the merged guard exceeds the scheduler's register-
// pressure knee and re-serializes the loads).
// ---------------------------------------------------------------------------
constexpr int QS = 6 * 72 * 32;            // 13824 B per q partition (432 entries)
constexpr int XS_BYTES = 4 * QS;           // 55296

__global__ __launch_bounds__(512, 2) void k_fused(const float* __restrict__ x,
                                                  const unsigned short* __restrict__ wOfrag,
                                                  const float* __restrict__ b_off,
                                                  const unsigned short* __restrict__ wTfrag,
                                                  const float* __restrict__ b_def,
                                                  float* __restrict__ out) {
    __shared__ __align__(16) char xs[XS_BYTES];
    __shared__ float offsBuf[128][22];

    int bid = blockIdx.x;                  // grid = 1024; one image per XCD
    int swz = (bid & 7) * 128 + (bid >> 3);
    int b  = swz >> 7;                     // image
    int rem2 = swz & 127;
    int h  = (rem2 >> 1) << 1;             // even row; block covers h, h+1
    int w0 = (rem2 & 1) << 6;              // 0 or 64

    int tid  = threadIdx.x;
    int lane = tid & 63;
    int wave = tid >> 6;                   // 0..7

    // --- phase 0: stage x window -> xs (bf16, zero-padded OOB) ---
    {
        int col = tid % 72;
        int rem = tid / 72;
        for (int it = tid; it < 6912; it += 512) {
            int c4  = rem & 15;            // channel group of 4
            int r   = rem >> 4;            // 0..5
            int y    = h - 2 + r;
            int xcol = w0 - 3 + col;
            bf16x4 pk;
            if (((unsigned)y < (unsigned)H_) && ((unsigned)xcol < (unsigned)W_)) {
                const float* g = x + (((size_t)(b * C_ + c4 * 4) * H_ + y) * W_ + xcol);
                pk[0] = f2bf_s(g[0]);
                pk[1] = f2bf_s(g[H_ * W_]);
                pk[2] = f2bf_s(g[2 * H_ * W_]);
                pk[3] = f2bf_s(g[3 * H_ * W_]);
            } else {
                pk = (bf16x4){0, 0, 0, 0};
            }
            int q0 = c4 >> 2;
            int byte = q0 * QS + ((r * 72 + col) * 32) + (c4 & 3) * 8;
            byte ^= ((col & 7) << 4) ^ (q0 << 5);
            *reinterpret_cast<bf16x4*>(xs + byte) = pk;
            col += 8; rem += 7;
            if (col >= 72) { col -= 72; rem += 1; }
        }
    }
    __syncthreads();

    // --- phase 1: offset GEMM (A-frags straight from xs) -> offsBuf ---
    {
        f32x4 acc2[2];
        acc2[0] = (f32x4){0.f, 0.f, 0.f, 0.f};
        acc2[1] = (f32x4){0.f, 0.f, 0.f, 0.f};
        int g   = lane >> 4;
        int pxr = wave * 16 + (lane & 15);            // 0..127
        int rr  = pxr >> 6, cx = pxr & 63;
        #pragma unroll
        for (int kc = 0; kc < 18; ++kc) {
            int K   = kc * 32 + g * 8;
            int tap = K >> 6, c = K & 63;
            int ky = tap / 3, kx = tap % 3;
            int col = cx + kx + 2;
            int r   = rr + ky + 1;
            int qq  = c >> 4;
            int byte = qq * QS + ((r * 72 + col) * 32) + (c & 15) * 2;
            byte ^= ((col & 7) << 4) ^ (qq << 5);
            bf16x8 a  = *reinterpret_cast<const bf16x8*>(xs + byte);
            bf16x8 b0 = *reinterpret_cast<const bf16x8*>(wOfrag + (((kc * 2 + 0) * 64 + lane) << 3));
            bf16x8 b1 = *reinterpret_cast<const bf16x8*>(wOfrag + (((kc * 2 + 1) * 64 + lane) << 3));
            acc2[0] = __builtin_amdgcn_mfma_f32_16x16x32_bf16(a, b0, acc2[0], 0, 0, 0);
            acc2[1] = __builtin_amdgcn_mfma_f32_16x16x32_bf16(a, b1, acc2[1], 0, 0, 0);
        }
        #pragma unroll
        for (int nt = 0; nt < 2; ++nt) {
            int oc = nt * 16 + (lane & 15);
            if (oc < OFFC) {
                float bo = b_off[oc];
                #pragma unroll
                for (int j = 0; j < 4; ++j) {
                    int px = wave * 16 + ((lane >> 4) << 2) + j;
                    offsBuf[px][oc] = acc2[nt][j] + bo;
                }
            }
        }
    }
    __syncthreads();

    // --- phase 2: pairwise-merged sample + MFMA ---
    f32x4 acc[4];
    #pragma unroll
    for (int nt = 0; nt < 4; ++nt) acc[nt] = (f32x4){0.f, 0.f, 0.f, 0.f};

    int g    = lane >> 4;                  // K-group 0..3
    int rowM = lane & 15;
    int pxw  = (wave << 4) + rowM;         // block-local px this lane samples
    int prr  = pxw >> 6, pcx = pxw & 63;   // sub-row (0/1), col in segment
    int glo  = (g & 1) << 4;               // byte offset of 8-ch half in entry
    int qlo  = g >> 1;                     // channels g*8..+8 -> q 0..1
    int qhi  = qlo + 2;                    // channels 32+g*8..+8 -> q 2..3
    int baseLo = qlo * QS + glo, baseHi = qhi * QS + glo;
    int xorLo  = qlo << 5,  xorHi  = qhi << 5;

    // preload all 9 offset pairs (one ds_read batch)
    float2 off9[9];
    #pragma unroll
    for (int k = 0; k < 9; ++k)
        off9[k] = *reinterpret_cast<const float2*>(&offsBuf[pxw][2 * k]);

// --- per-tap building blocks; S = name suffix, kk = tap index (literal) ---
#define TAPADDR(kk, S)                                                             \
    float py##S  = (float)(h + prr - 1 + ((kk) / 3)) + off9[kk].x;                 \
    float pxf##S = (float)(w0 + pcx - 1 + ((kk) % 3)) + off9[kk].y;                \
    float y0f##S = floorf(py##S), x0f##S = floorf(pxf##S);                         \
    float wy##S = py##S - y0f##S, wx##S = pxf##S - x0f##S;                         \
    int y0##S = (int)y0f##S, x0##S = (int)x0f##S;                                  \
    int r0##S = y0##S - (h - 2), c0##S = x0##S - (w0 - 3);                         \
    bool oow##S = ((unsigned)r0##S >= 5u) | ((unsigned)c0##S >= 71u);              \
    int rc##S = min(max(r0##S, 0), 4), cc##S = min(max(c0##S, 0), 70);             \
    float w00##S = (1.f - wy##S) * (1.f - wx##S);                                  \
    float w01##S = (1.f - wy##S) * wx##S;                                          \
    float w10##S = wy##S * (1.f - wx##S);                                          \
    float w11##S = wy##S * wx##S;                                                  \
    int A00##S = (rc##S * 72 + cc##S) << 5;                                        \
    int s0##S = (cc##S & 7) << 4;                                                  \
    int s1##S = ((cc##S + 1) & 7) << 4;

#define TAPLOAD(S)                                                                                 \
    uint4 l0##S = *reinterpret_cast<const uint4*>(xs + ((baseLo + A00##S)        ^ (s0##S ^ xorLo))); \
    uint4 l1##S = *reinterpret_cast<const uint4*>(xs + ((baseLo + A00##S + 32)   ^ (s1##S ^ xorLo))); \
    uint4 l2##S = *reinterpret_cast<const uint4*>(xs + ((baseLo + A00##S + 2304) ^ (s0##S ^ xorLo))); \
    uint4 l3##S = *reinterpret_cast<const uint4*>(xs + ((baseLo + A00##S + 2336) ^ (s1##S ^ xorLo))); \
    uint4 h0##S = *reinterpret_cast<const uint4*>(xs + ((baseHi + A00##S)        ^ (s0##S ^ xorHi))); \
    uint4 h1##S = *reinterpret_cast<const uint4*>(xs + ((baseHi + A00##S + 32)   ^ (s1##S ^ xorHi))); \
    uint4 h2##S = *reinterpret_cast<const uint4*>(xs + ((baseHi + A00##S + 2304) ^ (s0##S ^ xorHi))); \
    uint4 h3##S = *reinterpret_cast<const uint4*>(xs + ((baseHi + A00##S + 2336) ^ (s1##S ^ xorHi)));

#define TAPINTERP(S)                                                               \
    bf16x8 alo##S;                                                                 \
    {                                                                              \
        f32x2 L0 = bfpair(l0##S.x) * w00##S + bfpair(l1##S.x) * w01##S             \
                 + bfpair(l2##S.x) * w10##S + bfpair(l3##S.x) * w11##S;            \
        f32x2 L1 = bfpair(l0##S.y) * w00##S + bfpair(l1##S.y) * w01##S             \
                 + bfpair(l2##S.y) * w10##S + bfpair(l3##S.y) * w11##S;            \
        f32x2 L2 = bfpair(l0##S.z) * w00##S + bfpair(l1##S.z) * w01##S             \
                 + bfpair(l2##S.z) * w10##S + bfpair(l3##S.z) * w11##S;            \
        f32x2 L3 = bfpair(l0##S.w) * w00##S + bfpair(l1##S.w) * w01##S             \
                 + bfpair(l2##S.w) * w10##S + bfpair(l3##S.w) * w11##S;            \
        alo##S[0] = f2bf_s(L0[0]); alo##S[1] = f2bf_s(L0[1]);                      \
        alo##S[2] = f2bf_s(L1[0]); alo##S[3] = f2bf_s(L1[1]);                      \
        alo##S[4] = f2bf_s(L2[0]); alo##S[5] = f2bf_s(L2[1]);                      \
        alo##S[6] = f2bf_s(L3[0]); alo##S[7] = f2bf_s(L3[1]);                      \
    }                                                                              \
    bf16x8 ahi##S;                                                                 \
    {                                                                              \
        f32x2 H0 = bfpair(h0##S.x) * w00##S + bfpair(h1##S.x) * w01##S             \
                 + bfpair(h2##S.x) * w10##S + bfpair(h3##S.x) * w11##S;            \
        f32x2 H1 = bfpair(h0##S.y) * w00##S + bfpair(h1##S.y) * w01##S             \
                 + bfpair(h2##S.y) * w10##S + bfpair(h3##S.y) * w11##S;            \
        f32x2 H2 = bfpair(h0##S.z) * w00##S + bfpair(h1##S.z) * w01##S             \
                 + bfpair(h2##S.z) * w10##S + bfpair(h3##S.z) * w11##S;            \
        f32x2 H3 = bfpair(h0##S.w) * w00##S + bfpair(h1##S.w) * w01##S             \
                 + bfpair(h2##S.w) * w10##S + bfpair(h3##S.w) * w11##S;            \
        ahi##S[0] = f2bf_s(H0[0]); ahi##S[1] = f2bf_s(H0[1]);                      \
        ahi##S[2] = f2bf_s(H1[0]); ahi##S[3] = f2bf_s(H1[1]);                      \
        ahi##S[4] = f2bf_s(H2[0]); ahi##S[5] = f2bf_s(H2[1]);                      \
        ahi##S[6] = f2bf_s(H3[0]); ahi##S[7] = f2bf_s(H3[1]);                      \
    }

#define PATCHBODY(S)                                                               \
    {                                                                              \
        int y1 = y0##S + 1, x1 = x0##S + 1;                                        \
        bool vy0 = (y0##S >= 0) & (y0##S < H_);                                    \
        bool vy1 = (y1 >= 0) & (y1 < H_);                                          \
        bool vx0 = (x0##S >= 0) & (x0##S < W_);                                    \
        bool vx1 = (x1 >= 0) & (x1 < W_);                                          \
        float m00 = (vy0 && vx0) ? w00##S : 0.f;                                   \
        float m01 = (vy0 && vx1) ? w01##S : 0.f;                                   \
        float m10 = (vy1 && vx0) ? w10##S : 0.f;                                   \
        float m11 = (vy1 && vx1) ? w11##S : 0.f;                                   \
        int y0c = min(max(y0##S, 0), H_ - 1), y1c = min(max(y1, 0), H_ - 1);       \
        int x0c = min(max(x0##S, 0), W_ - 1), x1c = min(max(x1, 0), W_ - 1);       \
        int i00 = y0c * W_ + x0c, i01 = y0c * W_ + x1c;                            \
        int i10 = y1c * W_ + x0c, i11 = y1c * W_ + x1c;                            \
        const float* cb = x + (size_t)b * C_ * H_ * W_;                            \
        _Pragma("unroll")                                                          \
        for (int j = 0; j < 8; ++j) {                                              \
            const float* cA = cb + (size_t)((g << 3) + j) * (H_ * W_);             \
            const float* cB = cb + (size_t)(32 + (g << 3) + j) * (H_ * W_);        \
            alo##S[j] = f2bf_s(m00 * tobf_f(cA[i00]) + m01 * tobf_f(cA[i01])       \
                             + m10 * tobf_f(cA[i10]) + m11 * tobf_f(cA[i11]));     \
            ahi##S[j] = f2bf_s(m00 * tobf_f(cB[i00]) + m01 * tobf_f(cB[i01])       \
                             + m10 * tobf_f(cB[i10]) + m11 * tobf_f(cB[i11]));     \
        }                                                                          \
    }

#define TAPMFMA(kk, S)                                                             \
    {                                                                              \
        bf16x8 B0[4], B1[4];                                                       \
        _Pragma("unroll")                                                          \
        for (int nt = 0; nt < 4; ++nt) {                                           \
            B0[nt] = *reinterpret_cast<const bf16x8*>(                             \
                wTfrag + ((((2 * (kk) + 0) * 4 + nt) * 64 + lane) << 3));          \
            B1[nt] = *reinterpret_cast<const bf16x8*>(                             \
                wTfrag + ((((2 * (kk) + 1) * 4 + nt) * 64 + lane) << 3));          \
        }                                                                          \
        _Pragma("unroll")                                                          \
        for (int nt = 0; nt < 4; ++nt)                                             \
            acc[nt] = __builtin_amdgcn_mfma_f32_16x16x32_bf16(alo##S, B0[nt], acc[nt], 0, 0, 0); \
        _Pragma("unroll")                                                          \
        for (int nt = 0; nt < 4; ++nt)                                             \
            acc[nt] = __builtin_amdgcn_mfma_f32_16x16x32_bf16(ahi##S, B1[nt], acc[nt], 0, 0, 0); \
    }

#define PAIR(kA, kB)                                                               \
    {                                                                              \
        TAPADDR(kA, Pa) TAPADDR(kB, Pb)                                            \
        TAPLOAD(Pa) TAPLOAD(Pb)                                                    \
        TAPINTERP(Pa) TAPINTERP(Pb)                                                \
        if (__any(oowPa | oowPb)) {                                                \
            if (oowPa) PATCHBODY(Pa)                                               \
            if (oowPb) PATCHBODY(Pb)                                               \
        }                                                                          \
        TAPMFMA(kA, Pa) TAPMFMA(kB, Pb)                                            \
    }

#define SINGLE(kA)                                                                 \
    {                                                                              \
        TAPADDR(kA, Ps)                                                            \
        TAPLOAD(Ps)                                                                \
        TAPINTERP(Ps)                                                              \
        if (__any(oowPs)) {                                                        \
            if (oowPs) PATCHBODY(Ps)                                               \
        }                                                                          \
        TAPMFMA(kA, Ps)                                                            \
    }

    PAIR(0, 1)
    PAIR(2, 3)
    PAIR(4, 5)
    PAIR(6, 7)
    SINGLE(8)

#undef TAPADDR
#undef TAPLOAD
#undef TAPINTERP
#undef PATCHBODY
#undef TAPMFMA
#undef PAIR
#undef SINGLE

    // --- epilogue: direct float4 stores (proven r12/r13; r9's row split) ---
    int pxbase = (wave << 4) + (g << 2);   // 0..124, no 64-boundary crossing
    int rr = pxbase >> 6, cx = pxbase & 63;
    #pragma unroll
    for (int nt = 0; nt < 4; ++nt) {
        int oc = (nt << 4) + rowM;
        float bz = b_def[oc];
        float4 v;
        v.x = acc[nt][0] + bz;
        v.y = acc[nt][1] + bz;
        v.z = acc[nt][2] + bz;
        v.w = acc[nt][3] + bz;
        float* dst = out + (((size_t)b * O_ + oc) * H_ + h + rr) * W_ + w0 + cx;
        *reinterpret_cast<float4*>(dst) = v;
    }
}

// ---------------------------------------------------------------------------
extern "C" void kernel_launch(void* const* d_in, const int* in_sizes, int n_in,
                              void* d_out, int out_size, void* d_ws, size_t ws_size,
                              hipStream_t stream) {
    const float* x     = (const float*)d_in[0];
    const float* w_off = (const float*)d_in[1];
    const float* b_off = (const float*)d_in[2];
    const float* w_def = (const float*)d_in[3];
    const float* b_def = (const float*)d_in[4];
    float* out = (float*)d_out;

    char* ws = (char*)d_ws;
    unsigned short* wTf = (unsigned short*)ws;            // 73,728 B
    unsigned short* wOf = (unsigned short*)(ws + 73728);  // 36,864 B

    k_wprep<<<(O_ * C_ * K2_ + 255) / 256, 256, 0, stream>>>(w_def, wTf);
    k_wprep_off<<<(36 * 512 + 255) / 256, 256, 0, stream>>>(w_off, wOf);
    k_fused<<<NPIX / 128, 512, 0, stream>>>(x, wOf, b_off, wTf, b_def, out);
}